// Round 1
// 164.481 us; speedup vs baseline: 1.0090x; 1.0090x over previous
//
#include <hip/hip_runtime.h>

#define N_DRUG 20000
#define N_PROT 8000
#define D_DRUG 300
#define D_PROT 1280
#define HIDDEN 512
#define OUT_D  5
#define N_EDGE 500000
#define N_LBL  200000
#define WLD    812        // W_lin leading dim (300+512)
#define CAP    128        // bucket capacity (deg ~ 62.5 +- 7.9; 128 ~ 8 sigma)
#define OVF_MAX 65536     // exact overflow list capacity (never expected to fill)
#define CNT_STRIDE 32     // one counter per 128B L2 line: kills same-line atomic serialization
#define SCAT_B 245        // ceil(500000 / 2048)

// =========================================================================
// k0: weight folding WITHOUT atomics (8-lane shfl reduce over h-split) so
// A/B/c need no zero-init; spare blocks zero the padded cnt[] + novf.
// This removes the hipMemsetAsync dispatch AND frees the scatter to run
// concurrently with the dense stage in k1.
//   blocks [0,248):    fold A/B/c  (8 lanes per output element, 64 h each)
//   blocks [248,504):  zero cnt (1 MiB padded) + novf
// =========================================================================
__global__ void k_fold_zero(const float* __restrict__ W_l, const float* __restrict__ W_r,
                            const float* __restrict__ W_lin, const float* __restrict__ b_l,
                            float* __restrict__ A, float* __restrict__ B, float* __restrict__ c,
                            float4* __restrict__ cntz, int* __restrict__ novf) {
    int b = blockIdx.x;
    if (b < 248) {
        int t  = b * 256 + threadIdx.x;   // [0, 63488)
        int e  = t >> 3;                  // output element [0, 7936)
        int j  = t & 7;                   // h-chunk lane
        int h0 = j * 64;
        const int nA = OUT_D * D_DRUG;    // 1500
        const int nB = OUT_D * D_PROT;    // 6400
        float s = 0.f;
        if (e < nA) {
            int o = e / D_DRUG, k = e - o * D_DRUG;
            const float* wp = W_lin + o * WLD + D_DRUG + h0;
            const float* w  = W_l + (size_t)h0 * D_DRUG + k;
#pragma unroll 8
            for (int h = 0; h < 64; ++h) s += wp[h] * w[h * D_DRUG];
        } else if (e < nA + nB) {
            int u = e - nA;
            int o = u / D_PROT, k = u - o * D_PROT;
            const float* wp = W_lin + o * WLD + D_DRUG + h0;
            const float* w  = W_r + (size_t)h0 * D_PROT + k;
#pragma unroll 8
            for (int h = 0; h < 64; ++h) s += wp[h] * w[h * D_PROT];
        } else if (e < nA + nB + OUT_D) {
            int o = e - nA - nB;
            const float* wp = W_lin + o * WLD + D_DRUG + h0;
#pragma unroll 8
            for (int h = 0; h < 64; ++h) s += wp[h] * b_l[h0 + h];
        }
        // reduce the 8 h-chunks within each 8-lane group
        s += __shfl_xor(s, 1, 64);
        s += __shfl_xor(s, 2, 64);
        s += __shfl_xor(s, 4, 64);
        if (j == 0) {
            if (e < nA)                     A[e] = s;
            else if (e < nA + nB)           B[e - nA] = s;
            else if (e < nA + nB + OUT_D)   c[e - nA - nB] = s;
        }
    } else {
        // zero padded cnt: 8192 * 32 ints = 1 MiB = 65536 float4 (exact, no guard)
        int idx = (b - 248) * 256 + threadIdx.x;   // [0, 65536)
        cntz[idx] = make_float4(0.f, 0.f, 0.f, 0.f);
        if (idx == 0) *novf = 0;
    }
}

// =========================================================================
// k1: bucketed edge scatter RUNS CONCURRENTLY with both dense projections.
//   blocks [0,245):       scatter  r = cnt[d*32]++; bucket[d*CAP+r] = s
//                         (padded counters: 1 per 128B line -> 32x less
//                          same-line atomic serialization at L2)
//   blocks [245,1495):    P_A = x_drug@A.T, drugO = x_drug@Wlin_d.T (16 ln/row)
//   blocks [1495,3495):   protO = x_prot@B.T + c                    (64 ln/row)
// The ~65MB dense HBM stream hides the scatter's atomic latency.
// =========================================================================
__global__ void k_scatter_dense(const float* __restrict__ x_drug, const float* __restrict__ x_prot,
                                const int* __restrict__ edge_src, const int* __restrict__ edge_dst,
                                const float* __restrict__ A, const float* __restrict__ B,
                                const float* __restrict__ c, const float* __restrict__ W_lin,
                                int* __restrict__ cnt, int* __restrict__ novf,
                                int* __restrict__ bucket, int* __restrict__ ovf,
                                float* __restrict__ P_A, float* __restrict__ drugO,
                                float* __restrict__ protO) {
    int b = blockIdx.x;
    if (b < SCAT_B) {
        int base = b * 2048 + threadIdx.x;
#pragma unroll
        for (int i = 0; i < 8; ++i) {
            int e = base + i * 256;
            if (e < N_EDGE) {
                int s = edge_src[e], d = edge_dst[e];
                int r = atomicAdd(&cnt[d * CNT_STRIDE], 1);
                if (r < CAP) {
                    bucket[d * CAP + r] = s;
                } else {
                    int o = atomicAdd(novf, 1);
                    if (o < OVF_MAX) { ovf[2 * o] = d; ovf[2 * o + 1] = s; }
                }
            }
        }
    } else if (b < SCAT_B + 1250) {
        int gid = (b - SCAT_B) * 256 + threadIdx.x;
        int row = gid >> 4;              // 1250*256/16 = 20000 exactly
        int sub = threadIdx.x & 15;
        const float4* xr = (const float4*)(x_drug + (size_t)row * D_DRUG);  // 75 float4
        float acc[10];
#pragma unroll
        for (int i = 0; i < 10; ++i) acc[i] = 0.f;
        for (int k = sub; k < D_DRUG / 4; k += 16) {
            float4 x = xr[k];
#pragma unroll
            for (int o = 0; o < OUT_D; ++o) {
                float4 a = ((const float4*)(A + o * D_DRUG))[k];
                acc[o] += x.x * a.x + x.y * a.y + x.z * a.z + x.w * a.w;
                float4 w = ((const float4*)(W_lin + o * WLD))[k];
                acc[5 + o] += x.x * w.x + x.y * w.y + x.z * w.z + x.w * w.w;
            }
        }
#pragma unroll
        for (int i = 0; i < 10; ++i) {
            float v = acc[i];
            for (int m = 8; m; m >>= 1) v += __shfl_xor(v, m, 64);
            acc[i] = v;
        }
        if (sub < OUT_D) {
            P_A[row * OUT_D + sub]   = acc[sub];
            drugO[row * OUT_D + sub] = acc[5 + sub];
        }
    } else {
        int wave = ((b - SCAT_B - 1250) * 256 + threadIdx.x) >> 6;  // 2000*256/64 = 8000
        int lane = threadIdx.x & 63;
        const float4* xr = (const float4*)(x_prot + (size_t)wave * D_PROT);  // 320 float4
        float acc[OUT_D] = {0.f, 0.f, 0.f, 0.f, 0.f};
        for (int k = lane; k < D_PROT / 4; k += 64) {
            float4 x = xr[k];
#pragma unroll
            for (int o = 0; o < OUT_D; ++o) {
                float4 bb = ((const float4*)(B + o * D_PROT))[k];
                acc[o] += x.x * bb.x + x.y * bb.y + x.z * bb.z + x.w * bb.w;
            }
        }
#pragma unroll
        for (int o = 0; o < OUT_D; ++o) {
            float v = acc[o];
            for (int off = 32; off; off >>= 1) v += __shfl_xor(v, off, 64);
            acc[o] = v;
        }
        if (lane < OUT_D) protO[wave * OUT_D + lane] = acc[lane] + c[lane];
    }
}

// =========================================================================
// k2: bucket gather-mean, added into protO (one wave per protein)
// grid MUST be N_PROT*64/256 = 2000 blocks
// =========================================================================
__global__ void k_gather(const int* __restrict__ cnt, const int* __restrict__ novf,
                         const int* __restrict__ bucket, const int* __restrict__ ovf,
                         const float* __restrict__ P_A, float* __restrict__ protO) {
    int wave = (blockIdx.x * blockDim.x + threadIdx.x) >> 6;
    int lane = threadIdx.x & 63;
    if (wave >= N_PROT) return;
    int deg = cnt[wave * CNT_STRIDE];
    int m = deg < CAP ? deg : CAP;
    float acc[OUT_D] = {0.f, 0.f, 0.f, 0.f, 0.f};
    const int* br = &bucket[wave * CAP];
    for (int j = lane; j < m; j += 64) {
        const float* p = &P_A[br[j] * OUT_D];
#pragma unroll
        for (int o = 0; o < OUT_D; ++o) acc[o] += p[o];
    }
    if (deg > CAP) {   // exact tail: scan the tiny overflow list
        int nv = *novf; if (nv > OVF_MAX) nv = OVF_MAX;
        for (int j = lane; j < nv; j += 64) {
            if (ovf[2 * j] == wave) {
                const float* p = &P_A[ovf[2 * j + 1] * OUT_D];
#pragma unroll
                for (int o = 0; o < OUT_D; ++o) acc[o] += p[o];
            }
        }
    }
#pragma unroll
    for (int o = 0; o < OUT_D; ++o) {
        float v = acc[o];
        for (int off = 32; off; off >>= 1) v += __shfl_xor(v, off, 64);
        acc[o] = v;
    }
    if (lane < OUT_D)
        protO[wave * OUT_D + lane] += acc[lane] / fmaxf((float)deg, 1.f);
}

// =========================================================================
// k3: final gather-add
// =========================================================================
__global__ void k_final(const int* __restrict__ lbl_src, const int* __restrict__ lbl_dst,
                        const float* __restrict__ drugO, const float* __restrict__ protO,
                        const float* __restrict__ b_lin, float* __restrict__ out) {
    int l = blockIdx.x * blockDim.x + threadIdx.x;
    if (l >= N_LBL) return;
    int s = lbl_src[l], d = lbl_dst[l];
    const float* dr = &drugO[s * OUT_D];
    const float* pr = &protO[d * OUT_D];
    float* op = &out[(size_t)l * OUT_D];
    op[0] = dr[0] + pr[0] + b_lin[0];
    op[1] = dr[1] + pr[1] + b_lin[1];
    op[2] = dr[2] + pr[2] + b_lin[2];
    op[3] = dr[3] + pr[3] + b_lin[3];
    op[4] = dr[4] + pr[4] + b_lin[4];
}

extern "C" void kernel_launch(void* const* d_in, const int* in_sizes, int n_in,
                              void* d_out, int out_size, void* d_ws, size_t ws_size,
                              hipStream_t stream) {
    const float* x_drug   = (const float*)d_in[0];
    const float* x_prot   = (const float*)d_in[1];
    const int*   edge_src = (const int*)d_in[2];
    const int*   edge_dst = (const int*)d_in[3];
    const int*   lbl_src  = (const int*)d_in[4];
    const int*   lbl_dst  = (const int*)d_in[5];
    const float* W_l      = (const float*)d_in[6];
    const float* b_l      = (const float*)d_in[7];
    const float* W_r      = (const float*)d_in[8];
    const float* W_lin    = (const float*)d_in[9];
    const float* b_lin    = (const float*)d_in[10];
    float* out = (float*)d_out;

    // workspace layout (all zero-init handled inside k0; no memset dispatch)
    char* ws = (char*)d_ws;
    int*   cnt    = (int*)  (ws + 0);          // 1,048,576 B (8192 x 32 ints, padded)
    int*   novf   = (int*)  (ws + 1048576);    //        16 B
    float* A      = (float*)(ws + 1048592);    //     6,000 B (5x300)
    float* B      = (float*)(ws + 1054592);    //    25,600 B (5x1280)
    float* c      = (float*)(ws + 1080192);    //        20 B
    float* P_A    = (float*)(ws + 1080320);    //   400,000 B
    float* drugO  = (float*)(ws + 1480320);    //   400,000 B
    float* protO  = (float*)(ws + 1880320);    //   160,000 B
    int*   bucket = (int*)  (ws + 2040320);    // 4,096,000 B (8000 x 128)
    int*   ovf    = (int*)  (ws + 6136320);    //   524,288 B (65536 pairs)
    // total: 6,660,608 B

    k_fold_zero<<<504, 256, 0, stream>>>(W_l, W_r, W_lin, b_l, A, B, c,
                                         (float4*)cnt, novf);
    k_scatter_dense<<<3495, 256, 0, stream>>>(x_drug, x_prot, edge_src, edge_dst,
                                              A, B, c, W_lin, cnt, novf, bucket, ovf,
                                              P_A, drugO, protO);
    k_gather<<<2000, 256, 0, stream>>>(cnt, novf, bucket, ovf, P_A, protO);
    k_final<<<(N_LBL + 255) / 256, 256, 0, stream>>>(lbl_src, lbl_dst, drugO, protO, b_lin, out);
}